// Round 1
// baseline (580.395 us; speedup 1.0000x reference)
//
#include <hip/hip_runtime.h>
#include <hip/hip_bf16.h>

// Problem constants (B,H,L,D)=(8,12,1024,768), K=512
constexpr int B = 8;
constexpr int H = 12;
constexpr int L = 1024;
constexpr int D = 768;
constexpr int K = 512;

constexpr int ROWS   = H * L;          // 12288 rows per batch (h,i flattened)
constexpr int NCHUNK = 96;             // partial chunks per batch
constexpr int CHUNK  = ROWS / NCHUNK;  // 128 rows per block

// ---------------------------------------------------------------------------
// Kernel 1: deterministic partial column sums of scores.
// grid = B*NCHUNK blocks, 256 threads. Thread t owns columns 4t..4t+3 (float4).
// Each block sums CHUNK contiguous rows -> partial[b][chunk][0..L).
// ---------------------------------------------------------------------------
__global__ __launch_bounds__(256) void colsum_partial_kernel(
    const float* __restrict__ scores, float* __restrict__ partial) {
    const int bc = blockIdx.x;
    const int b = bc / NCHUNK;
    const int c = bc % NCHUNK;
    const int t = threadIdx.x;  // 0..255 -> float4 column index

    const float4* src = (const float4*)(scores + (size_t)b * ROWS * L)
                        + (size_t)(c * CHUNK) * (L / 4) + t;
    float4 acc = make_float4(0.f, 0.f, 0.f, 0.f);
#pragma unroll 8
    for (int r = 0; r < CHUNK; ++r) {
        float4 v = src[(size_t)r * (L / 4)];
        acc.x += v.x; acc.y += v.y; acc.z += v.z; acc.w += v.w;
    }
    ((float4*)(partial + (size_t)(b * NCHUNK + c) * L))[t] = acc;
}

// ---------------------------------------------------------------------------
// Kernel 2: reduce partials -> importance, then top-K by rank counting,
// compact selected indices in ascending order (== jnp.sort(top_k idx)).
// grid = B blocks, 1024 threads (thread j owns column j).
// Tie-break matches jax.lax.top_k: larger value first; equal value -> lower idx.
// ---------------------------------------------------------------------------
__global__ __launch_bounds__(1024) void topk_kernel(
    const float* __restrict__ partial, int* __restrict__ idx_out) {
    const int b = blockIdx.x;
    const int j = threadIdx.x;  // 0..1023

    __shared__ float v[L];
    __shared__ int wave_tot[16];
    __shared__ int wave_pref[16];

    // Deterministic fixed-order reduction of the 96 partials.
    const float* p = partial + (size_t)b * NCHUNK * L + j;
    float s = 0.f;
#pragma unroll 8
    for (int c = 0; c < NCHUNK; ++c) s += p[(size_t)c * L];
    const float val = s * (1.0f / (float)H);
    v[j] = val;
    __syncthreads();

    // rank = #elements strictly greater, or equal with smaller index.
    int rank = 0;
    for (int jj = 0; jj < L; ++jj) {
        float u = v[jj];
        rank += (u > val) || (u == val && jj < j);
    }
    const bool sel = (rank < K);

    // Block-wide compaction: ballot within wave + cross-wave scan.
    const int lane = j & 63;
    const int wave = j >> 6;
    unsigned long long ball = __ballot(sel);
    int within = __popcll(ball & ((1ull << lane) - 1ull));
    if (lane == 0) wave_tot[wave] = __popcll(ball);
    __syncthreads();
    if (j == 0) {
        int run = 0;
        for (int w = 0; w < 16; ++w) { wave_pref[w] = run; run += wave_tot[w]; }
    }
    __syncthreads();
    if (sel) idx_out[b * K + wave_pref[wave] + within] = j;
}

// ---------------------------------------------------------------------------
// Kernel 3: gather rows + mask. grid = B*(K+1) blocks, 192 threads (float4/row).
// Output layout: final_token [B][K+1][D] then final_mask [B][K+1].
// ---------------------------------------------------------------------------
__global__ __launch_bounds__(192) void gather_kernel(
    const float* __restrict__ hidden, const float* __restrict__ amask,
    const int* __restrict__ idx, float* __restrict__ out) {
    const int m = blockIdx.x;        // 0..B*(K+1)-1
    const int b = m / (K + 1);
    const int r = m % (K + 1);
    const int src = (r == 0) ? 0 : idx[b * K + r - 1];

    const float4* srow = (const float4*)(hidden + (size_t)(b * L + src) * D);
    float4* drow = (float4*)(out + (size_t)m * D);
    drow[threadIdx.x] = srow[threadIdx.x];

    if (threadIdx.x == 0) {
        float mv = (r == 0) ? 0.0f : amask[b * L + src];
        out[(size_t)B * (K + 1) * D + m] = mv;
    }
}

extern "C" void kernel_launch(void* const* d_in, const int* in_sizes, int n_in,
                              void* d_out, int out_size, void* d_ws, size_t ws_size,
                              hipStream_t stream) {
    const float* hidden = (const float*)d_in[0];  // (B, L, D) fp32
    const float* amask  = (const float*)d_in[1];  // (B, 1, 1, L) fp32
    const float* scores = (const float*)d_in[2];  // (B, H, L, L) fp32
    float* out = (float*)d_out;

    float* partial = (float*)d_ws;                                  // B*NCHUNK*L fp32 (3 MB)
    int*   idx     = (int*)((char*)d_ws +
                            (size_t)B * NCHUNK * L * sizeof(float)); // B*K ints (16 KB)

    colsum_partial_kernel<<<B * NCHUNK, 256, 0, stream>>>(scores, partial);
    topk_kernel<<<B, 1024, 0, stream>>>(partial, idx);
    gather_kernel<<<B * (K + 1), 192, 0, stream>>>(hidden, amask, idx, out);
}